// Round 3
// baseline (59238.354 us; speedup 1.0000x reference)
//
#include <hip/hip_runtime.h>
#include <hip/hip_bf16.h>

#define BB 32
#define TT 1000
#define HH 512
#define H2 1024
#define H4 2048
#define VV 10000
#define LL 100
#define NBLK 256
#define NBGEMM 160

typedef unsigned short u16;
typedef unsigned int u32;
typedef short short8 __attribute__((ext_vector_type(8)));
typedef float f32x4 __attribute__((ext_vector_type(4)));

__device__ __forceinline__ float bf2f(u16 s){ return __uint_as_float(((u32)s)<<16); }
__device__ __forceinline__ u16 f2bf(float f){
  u32 u = __float_as_uint(f);
  u32 r = (u + 0x7fffu + ((u>>16)&1u)) >> 16;
  return (u16)r;
}
__device__ __forceinline__ float fast_tanh(float x){
  float e = __expf(2.0f*x);
  return 1.0f - 2.0f/(e+1.0f);
}
__device__ __forceinline__ float sigm(float x){ return 0.5f*fast_tanh(0.5f*x)+0.5f; }

__device__ __forceinline__ f32x4 mfma16(short8 a, short8 b, f32x4 c){
  return __builtin_amdgcn_mfma_f32_16x16x32_bf16(a, b, c, 0, 0, 0);
}

__device__ __forceinline__ void ld8(const float* __restrict__ p, float* v){
  float4 a = *(const float4*)p, b = *(const float4*)(p+4);
  v[0]=a.x; v[1]=a.y; v[2]=a.z; v[3]=a.w; v[4]=b.x; v[5]=b.y; v[6]=b.z; v[7]=b.w;
}

__device__ __forceinline__ int aload(int* p){
  return __hip_atomic_load(p, __ATOMIC_ACQUIRE, __HIP_MEMORY_SCOPE_AGENT);
}
__device__ __forceinline__ int aadd(int* p, int v){
  return __hip_atomic_fetch_add(p, v, __ATOMIC_ACQ_REL, __HIP_MEMORY_SCOPE_AGENT);
}

__device__ __forceinline__ void gridbar(int* bcnt, int& barid){
  barid++;
  __threadfence();
  __syncthreads();
  if (threadIdx.x == 0){
    aadd(bcnt, 1);
    const int target = NBLK * barid;
    while (aload(bcnt) < target) __builtin_amdgcn_s_sleep(2);
  }
  __syncthreads();
  __threadfence();
}

__global__ __launch_bounds__(256) void k_zero(float4* __restrict__ p, int n4){
  int i = blockIdx.x*256 + threadIdx.x;
  if (i < n4) p[i] = make_float4(0.f,0.f,0.f,0.f);
}

__global__ __launch_bounds__(256) void k_cvt_h(const float4* __restrict__ src,
    ushort4* __restrict__ dst, int n4){
  for (int i = blockIdx.x*256+threadIdx.x; i < n4; i += gridDim.x*256){
    float4 v = src[i];
    ushort4 o; o.x=f2bf(v.x); o.y=f2bf(v.y); o.z=f2bf(v.z); o.w=f2bf(v.w);
    dst[i]=o;
  }
}

// generic B-fragment swizzle: dst[nt][kt][lane][8]; (n,k) from up to 3 col-spaces
__global__ __launch_bounds__(256) void k_swz(u16* __restrict__ dst, int NT, int KT,
    const float* s0, int n0, int ld0, const float* s1, int n1, int ld1,
    const float* s2, int n2, int ld2)
{
  int gid = blockIdx.x*256+threadIdx.x;
  int total = NT*KT*64;
  if (gid >= total) return;
  int l = gid & 63;
  int kt = (gid >> 6) % KT;
  int nt = gid / (KT*64);
  int n = nt*16 + (l & 15);
  int k = kt*32 + ((l>>4)<<3);
  const float* sp = 0; int ld=0, col=0;
  if (n < n0){ sp=s0; ld=ld0; col=n; }
  else if (n < n0+n1){ sp=s1; ld=ld1; col=n-n0; }
  else if (n < n0+n1+n2){ sp=s2; ld=ld2; col=n-n0-n1; }
  short8 v;
  #pragma unroll 8
  for (int e=0;e<8;e++){
    float f = sp ? sp[(size_t)(k+e)*ld + col] : 0.f;
    v[e] = (short)f2bf(f);
  }
  *(short8*)(dst + (size_t)gid*8) = v;
}

// WstepF: K=1536 (g rows 0..1023, s rows 1024..1535), N=2560 (z cols 0..511, rec 512..2559)
__global__ __launch_bounds__(256) void k_swz2(u16* __restrict__ dst,
    const float* __restrict__ W_gy, const float* __restrict__ W_sy,
    const float* __restrict__ W_gr, const float* __restrict__ W_sr)
{
  int gid = blockIdx.x*256+threadIdx.x;
  if (gid >= NBGEMM*48*64) return;
  int l = gid & 63;
  int kt = (gid >> 6) % 48;
  int nt = gid / (48*64);
  int n = nt*16 + (l & 15);
  int k = kt*32 + ((l>>4)<<3);
  short8 v;
  #pragma unroll 8
  for (int e=0;e<8;e++){
    int kk = k + e;
    float f;
    if (n < HH) f = (kk < H2) ? W_gy[(size_t)kk*HH + n]       : W_sy[(size_t)(kk-H2)*HH + n];
    else { int q = n-HH; f = (kk < H2) ? W_gr[(size_t)kk*H4 + q] : W_sr[(size_t)(kk-H2)*H4 + q]; }
    v[e] = (short)f2bf(f);
  }
  *(short8*)(dst + (size_t)gid*8) = v;
}

// one-time: hp = h @ W_h_att + b_att (MFMA) -> bf16
__global__ __launch_bounds__(256) void k_hproj(const float* __restrict__ h,
  const u16* __restrict__ WhF, const float* __restrict__ b_att, u16* __restrict__ hp)
{
  const int tid = threadIdx.x, l = tid & 63, wv = tid >> 6;
  const int wm = wv >> 1, wn = wv & 1;
  const int Mbase = blockIdx.x*128 + wm*64;
  const int Nbase = blockIdx.y*128 + wn*64;
  const int arow = l & 15, ak = (l>>4)<<3;
  f32x4 acc[4][4] = {};
  for (int kt=0; kt<32; kt++){
    short8 a[4], b[4];
    #pragma unroll
    for (int mt=0;mt<4;mt++){
      const float* p = h + (size_t)(Mbase + mt*16 + arow)*H2 + kt*32 + ak;
      float vv[8]; ld8(p, vv);
      short8 t;
      #pragma unroll 8
      for (int e=0;e<8;e++) t[e] = (short)f2bf(vv[e]);
      a[mt]=t;
    }
    #pragma unroll
    for (int nt=0;nt<4;nt++){
      int ntg = (Nbase>>4) + nt;
      b[nt] = *(const short8*)(WhF + (((size_t)ntg*32 + kt)*64 + l)*8);
    }
    #pragma unroll
    for (int mt=0;mt<4;mt++)
      #pragma unroll
      for (int nt=0;nt<4;nt++)
        acc[mt][nt] = mfma16(a[mt], b[nt], acc[mt][nt]);
  }
  #pragma unroll
  for (int mt=0;mt<4;mt++)
    #pragma unroll
    for (int nt=0;nt<4;nt++){
      int n = Nbase + nt*16 + (l&15);
      float bias = b_att[n];
      #pragma unroll
      for (int r=0;r<4;r++){
        int row = Mbase + mt*16 + ((l>>4)<<2) + r;
        hp[(size_t)row*HH + n] = f2bf(acc[mt][nt][r] + bias);
      }
    }
}

// final: out = zF @ WyyF + b_yy   M=3200 N=10240(pad) K=512
__global__ __launch_bounds__(256) void k_ybig(const u16* __restrict__ zF,
  const u16* __restrict__ WyyF, const float* __restrict__ b_yy, float* __restrict__ out)
{
  const int tid=threadIdx.x, l=tid&63, wv=tid>>6;
  const int wm=wv>>1, wn=wv&1;
  const int mtB = blockIdx.x*8 + wm*4;
  const int ntB = blockIdx.y*8 + wn*4;
  f32x4 acc[4][4] = {};
  for (int kt=0; kt<16; kt++){
    short8 a[4], b[4];
    #pragma unroll
    for (int mt=0;mt<4;mt++)
      a[mt] = *(const short8*)(zF + (((size_t)(mtB+mt)*16 + kt)*64 + l)*8);
    #pragma unroll
    for (int nt=0;nt<4;nt++)
      b[nt] = *(const short8*)(WyyF + (((size_t)(ntB+nt)*16 + kt)*64 + l)*8);
    #pragma unroll
    for (int mt=0;mt<4;mt++)
      #pragma unroll
      for (int nt=0;nt<4;nt++)
        acc[mt][nt] = mfma16(a[mt], b[nt], acc[mt][nt]);
  }
  #pragma unroll
  for (int mt=0;mt<4;mt++)
    #pragma unroll
    for (int nt=0;nt<4;nt++){
      int n = (ntB+nt)*16 + (l&15);
      if (n < VV){
        float bias = b_yy[n];
        #pragma unroll
        for (int r=0;r<4;r++){
          int row = (mtB+mt)*16 + ((l>>4)<<2) + r;
          out[(size_t)row*VV + n] = acc[mt][nt][r] + bias;
        }
      }
    }
}

// ======== the whole 100-step scan: one cooperative kernel ========
__global__ __launch_bounds__(512) void k_scan(
  const u16* __restrict__ hp, const u16* __restrict__ hb,
  const float* __restrict__ w_att, const int* __restrict__ seq,
  float* __restrict__ proj_att, float* __restrict__ gpart, float* __restrict__ Zpart,
  u16* __restrict__ aF, const u16* __restrict__ WstepF, const u16* __restrict__ WprojF,
  const float* __restrict__ b_gy, const float* __restrict__ b_sy,
  const float* __restrict__ b_sr, const float* __restrict__ b_gr,
  const float* __restrict__ E_yr, const int* __restrict__ labels,
  u16* __restrict__ zF, float* __restrict__ rec, float* __restrict__ cbuf,
  int* cnt_b, int* cntB, int* bcnt)
{
  const int bid = blockIdx.x, tid = threadIdx.x;
  const int lane = tid & 63, wv = tid >> 6;
  __shared__ union {
    float sg[8][1024];
    float sC[8][64][8];
    float sS[32][516];
  } sm;
  __shared__ float szz[8];
  __shared__ int sflag;
  int barid = 0;
  const int fb = bid >> 3, fch = bid & 7;
  const int flen = seq[fb];
  const int ft0 = fch * 125;
  float wa[8];
  ld8(w_att + lane*8, wa);

  for (int ls = 0; ls < LL; ++ls){
    // ===== phase A: flash attention partials + last-block combine =====
    {
      float sw[8];
      ld8(proj_att + fb*HH + lane*8, sw);
      const int tmax = min(ft0 + 125, flen);
      float gacc[16];
      #pragma unroll 16
      for (int i=0;i<16;i++) gacc[i]=0.f;
      float zacc = 0.f;
      for (int t = ft0 + wv; t < tmax; t += 8){
        const uint4 hv = *(const uint4*)(hp + ((size_t)fb*TT + t)*HH + lane*8);
        u32 uu[4] = {hv.x,hv.y,hv.z,hv.w};
        float p = 0.f;
        #pragma unroll
        for (int q=0;q<4;q++){
          p += wa[2*q+0]*fast_tanh(bf2f((u16)(uu[q]&0xffffu))+sw[2*q+0]);
          p += wa[2*q+1]*fast_tanh(bf2f((u16)(uu[q]>>16))+sw[2*q+1]);
        }
        #pragma unroll
        for (int off=32; off; off>>=1) p += __shfl_xor(p, off, 64);
        float wgt = __expf(p);
        zacc += wgt;
        const uint4* hr = (const uint4*)(hb + ((size_t)fb*TT + t)*H2 + lane*16);
        uint4 h0 = hr[0], h1 = hr[1];
        u32 hh[8] = {h0.x,h0.y,h0.z,h0.w,h1.x,h1.y,h1.z,h1.w};
        #pragma unroll
        for (int q=0;q<8;q++){
          gacc[2*q+0] += wgt*bf2f((u16)(hh[q]&0xffffu));
          gacc[2*q+1] += wgt*bf2f((u16)(hh[q]>>16));
        }
      }
      #pragma unroll
      for (int q=0;q<4;q++)
        *(float4*)(&sm.sg[wv][lane*16+q*4]) = make_float4(gacc[4*q],gacc[4*q+1],gacc[4*q+2],gacc[4*q+3]);
      if (lane==0) szz[wv]=zacc;
      __syncthreads();
      {
        int e = tid*2;
        float v0=0.f, v1=0.f;
        #pragma unroll
        for (int w8=0;w8<8;w8++){ v0 += sm.sg[w8][e]; v1 += sm.sg[w8][e+1]; }
        *(float2*)(gpart + ((size_t)(fb*8+fch))*H2 + e) = make_float2(v0,v1);
        if (tid==0){
          float z=0.f;
          #pragma unroll
          for (int w8=0;w8<8;w8++) z += szz[w8];
          Zpart[fb*8+fch] = z;
        }
      }
      __threadfence();
      __syncthreads();
      if (tid==0){
        int old = aadd(&cnt_b[fb], 1);
        sflag = (old == 8*ls + 7);
      }
      __syncthreads();
      if (sflag){                 // last block for batch fb: combine -> aF (g part)
        __threadfence();
        float z = 0.f;
        #pragma unroll
        for (int c=0;c<8;c++) z += Zpart[fb*8+c];
        float inv = 1.f/z;
        const int mt = fb>>4, bl = fb&15;
        for (int q = tid; q < H2; q += 512){
          float s = 0.f;
          #pragma unroll
          for (int c=0;c<8;c++) s += gpart[((size_t)(fb*8+c))*H2 + q];
          int kt = q>>5, j=(q>>3)&3, e=q&7;
          aF[((size_t)(kt*2+mt)*64 + 16*j + bl)*8 + e] = f2bf(s*inv);
        }
      }
    }
    gridbar(bcnt, barid);
    // ===== phase B: [g|s](32x1536) @ Wstep(1536x2560) -> z->zF, rec =====
    {
      if (bid < NBGEMM){
        const int nt = bid;
        f32x4 acc0 = {0.f,0.f,0.f,0.f}, acc1 = {0.f,0.f,0.f,0.f};
        #pragma unroll
        for (int kk=0; kk<6; ++kk){
          int kt = wv*6 + kk;
          short8 bfr = *(const short8*)(WstepF + (((size_t)nt*48 + kt)*64 + lane)*8);
          short8 a0  = *(const short8*)(aF + ((size_t)(kt*2+0)*64 + lane)*8);
          short8 a1  = *(const short8*)(aF + ((size_t)(kt*2+1)*64 + lane)*8);
          acc0 = mfma16(a0, bfr, acc0);
          acc1 = mfma16(a1, bfr, acc1);
        }
        #pragma unroll
        for (int r=0;r<4;r++){ sm.sC[wv][lane][r] = acc0[r]; sm.sC[wv][lane][4+r] = acc1[r]; }
        __syncthreads();
        int lq = tid>>3, e = tid&7;
        float v = 0.f;
        #pragma unroll
        for (int w8=0;w8<8;w8++) v += sm.sC[w8][lq][e];
        int mtv = e>>2, r = e&3;
        int brow = mtv*16 + ((lq>>4)<<2) + r;
        int n = nt*16 + (lq&15);
        if (n < HH){
          float zv = fast_tanh(v + b_gy[n] + b_sy[n]);
          int row = brow*LL + ls;
          int mtg = row>>4, rr = row&15, ktz = n>>5;
          int lp = rr | (((n>>3)&3)<<4);
          zF[(((size_t)mtg*16+ktz)*64+lp)*8 + (n&7)] = f2bf(zv);
        } else {
          int q = n - HH;
          int tok = labels[brow*LL + ls];
          rec[(size_t)brow*H4 + q] = v + b_sr[q] + b_gr[q] + E_yr[(size_t)tok*H4 + q];
        }
      }
      __threadfence();
      __syncthreads();
      if (tid==0){
        int old = (bid < NBGEMM) ? aadd(cntB, 1) : -1;
        sflag = (old == NBGEMM*(ls+1) - 1);
      }
      __syncthreads();
      // ===== phase C (finisher block): LSTM + s-frags + proj_att GEMM =====
      if (sflag){
        __threadfence();
        const int b = tid>>4, q0 = (tid&15)*32;
        const float* rb  = rec + (size_t)b*H4;
        const float* cin = cbuf + (size_t)(ls&1)*BB*HH + b*HH;
        float*      cout = cbuf + (size_t)((ls+1)&1)*BB*HH + b*HH;
        const int mt = b>>4, bl = b&15;
        for (int qq=q0; qq<q0+32; qq+=8){
          float iv[8],fv[8],gv[8],ov[8],cv[8];
          ld8(rb+qq,iv); ld8(rb+HH+qq,fv); ld8(rb+H2+qq,gv); ld8(rb+1536+qq,ov);
          ld8(cin+qq,cv);
          float sv[8], cn[8];
          #pragma unroll 8
          for (int e=0;e<8;e++){
            float ii = sigm(iv[e]), ff = sigm(fv[e]);
            float cg = fast_tanh(gv[e]), oo = sigm(ov[e]);
            cn[e] = ff*cv[e] + ii*cg;
            sv[e] = oo*fast_tanh(cn[e]);
          }
          *(float4*)(cout+qq)   = make_float4(cn[0],cn[1],cn[2],cn[3]);
          *(float4*)(cout+qq+4) = make_float4(cn[4],cn[5],cn[6],cn[7]);
          #pragma unroll 8
          for (int e=0;e<8;e++){
            int q = qq+e;
            sm.sS[b][q] = sv[e];
            int kt = 32 + (q>>5), j=(q>>3)&3;
            aF[((size_t)(kt*2+mt)*64 + 16*j + bl)*8 + (q&7)] = f2bf(sv[e]);
          }
        }
        __syncthreads();
        f32x4 p0[4] = {}, p1[4] = {};
        for (int kt=0; kt<16; ++kt){
          int kbase = kt*32 + ((lane>>4)<<3);
          short8 a0, a1;
          {
            float vv[8];
            ld8(&sm.sS[lane&15][kbase], vv);
            #pragma unroll 8
            for (int e=0;e<8;e++) a0[e] = (short)f2bf(vv[e]);
            ld8(&sm.sS[16+(lane&15)][kbase], vv);
            #pragma unroll 8
            for (int e=0;e<8;e++) a1[e] = (short)f2bf(vv[e]);
          }
          #pragma unroll
          for (int j=0;j<4;j++){
            int nt2 = wv*4 + j;
            short8 bfr = *(const short8*)(WprojF + (((size_t)nt2*16 + kt)*64 + lane)*8);
            p0[j] = mfma16(a0, bfr, p0[j]);
            p1[j] = mfma16(a1, bfr, p1[j]);
          }
        }
        #pragma unroll
        for (int j=0;j<4;j++){
          int n = (wv*4+j)*16 + (lane&15);
          #pragma unroll
          for (int r=0;r<4;r++){
            int b0 = ((lane>>4)<<2) + r;
            proj_att[(size_t)b0*HH + n]      = p0[j][r];
            proj_att[(size_t)(16+b0)*HH + n] = p1[j][r];
          }
        }
      }
    }
    gridbar(bcnt, barid);
  }
}

extern "C" void kernel_launch(void* const* d_in, const int* in_sizes, int n_in,
                              void* d_out, int out_size, void* d_ws, size_t ws_size,
                              hipStream_t stream)
{
  (void)in_sizes; (void)n_in; (void)out_size; (void)ws_size;
  const float* h       = (const float*)d_in[0];
  const int*   seq     = (const int*)d_in[1];
  const int*   labels  = (const int*)d_in[2];
  const float* W_sy    = (const float*)d_in[3];
  const float* b_sy    = (const float*)d_in[4];
  const float* W_gy    = (const float*)d_in[5];
  const float* b_gy    = (const float*)d_in[6];
  const float* W_yy    = (const float*)d_in[7];
  const float* b_yy    = (const float*)d_in[8];
  const float* E_yr    = (const float*)d_in[9];
  const float* W_sr    = (const float*)d_in[10];
  const float* b_sr    = (const float*)d_in[11];
  const float* W_gr    = (const float*)d_in[12];
  const float* b_gr    = (const float*)d_in[13];
  const float* W_s_att = (const float*)d_in[14];
  const float* W_h_att = (const float*)d_in[15];
  const float* b_att   = (const float*)d_in[16];
  const float* w_att   = (const float*)d_in[17];
  float* out = (float*)d_out;

  char* w = (char*)d_ws;
  u16* hp      = (u16*)w;  w += (size_t)BB*TT*HH*2;          // 32.77 MB
  u16* hb      = (u16*)w;  w += (size_t)BB*TT*H2*2;          // 65.54 MB
  u16* WhF     = (u16*)w;  w += (size_t)32*32*64*8*2;        // 1.05 MB
  u16* WstepF  = (u16*)w;  w += (size_t)NBGEMM*48*64*8*2;    // 7.86 MB
  u16* WprojF  = (u16*)w;  w += (size_t)32*16*64*8*2;        // 0.52 MB
  u16* WyyF    = (u16*)w;  w += (size_t)640*16*64*8*2;       // 10.49 MB
  u16* zF      = (u16*)w;  w += (size_t)200*16*64*8*2;       // 3.28 MB
  float* gpart = (float*)w; w += (size_t)BB*8*H2*4;          // 1.05 MB
  float* Zpart = (float*)w; w += (size_t)BB*8*4;
  float* rec   = (float*)w; w += (size_t)BB*H4*4;
  // ---- zeroed-every-call region (contiguous) ----
  float* zbase    = (float*)w;
  float* proj_att = (float*)w; w += (size_t)BB*HH*4;         // 16384 f
  float* cbuf     = (float*)w; w += (size_t)2*BB*HH*4;       // 32768 f
  u16*   aF       = (u16*)w;  w += (size_t)48*2*64*8*2;      // 49152 u16 = 24576 f
  int*   cnts     = (int*)w;  w += 256;                      // 64 ints
  int* cnt_b = cnts, *cntB = cnts+32, *bcnt = cnts+33;
  const int nzero4 = (16384 + 32768 + 24576 + 64) / 4;       // 18448 float4

  k_cvt_h<<<2048,256,0,stream>>>((const float4*)h, (ushort4*)hb, BB*TT*H2/4);
  k_swz<<<256 ,256,0,stream>>>(WhF,   32,32, W_h_att,512,512, 0,0,0, 0,0,0);
  k_swz2<<<1920,256,0,stream>>>(WstepF, W_gy, W_sy, W_gr, W_sr);
  k_swz<<<128 ,256,0,stream>>>(WprojF, 32,16, W_s_att,512,512, 0,0,0, 0,0,0);
  k_swz<<<2560,256,0,stream>>>(WyyF, 640,16, W_yy,10000,10000, 0,0,0, 0,0,0);
  k_zero<<<(nzero4+255)/256,256,0,stream>>>((float4*)zbase, nzero4);
  k_hproj<<<dim3(250,4),256,0,stream>>>(h, WhF, b_att, hp);

  void* args[] = { (void*)&hp, (void*)&hb, (void*)&w_att, (void*)&seq,
                   (void*)&proj_att, (void*)&gpart, (void*)&Zpart, (void*)&aF,
                   (void*)&WstepF, (void*)&WprojF,
                   (void*)&b_gy, (void*)&b_sy, (void*)&b_sr, (void*)&b_gr,
                   (void*)&E_yr, (void*)&labels, (void*)&zF, (void*)&rec,
                   (void*)&cbuf, (void*)&cnt_b, (void*)&cntB, (void*)&bcnt };
  hipLaunchCooperativeKernel((const void*)k_scan, dim3(NBLK), dim3(512), args, 0, stream);

  k_ybig<<<dim3(25,80),256,0,stream>>>(zF, WyyF, b_yy, out);
}

// Round 4
// 8039.788 us; speedup vs baseline: 7.3681x; 7.3681x over previous
//
#include <hip/hip_runtime.h>
#include <hip/hip_bf16.h>

#define BB 32
#define TT 1000
#define HH 512
#define H2 1024
#define H4 2048
#define VV 10000
#define LL 100
#define NBLK 256
#define NBGEMM 160

typedef unsigned short u16;
typedef unsigned int u32;
typedef short short8 __attribute__((ext_vector_type(8)));
typedef float f32x4 __attribute__((ext_vector_type(4)));

__device__ __forceinline__ float bf2f(u16 s){ return __uint_as_float(((u32)s)<<16); }
__device__ __forceinline__ u16 f2bf(float f){
  u32 u = __float_as_uint(f);
  u32 r = (u + 0x7fffu + ((u>>16)&1u)) >> 16;
  return (u16)r;
}
__device__ __forceinline__ float fast_tanh(float x){
  float e = __expf(2.0f*x);
  return 1.0f - 2.0f/(e+1.0f);
}
__device__ __forceinline__ float sigm(float x){ return 0.5f*fast_tanh(0.5f*x)+0.5f; }

__device__ __forceinline__ f32x4 mfma16(short8 a, short8 b, f32x4 c){
  return __builtin_amdgcn_mfma_f32_16x16x32_bf16(a, b, c, 0, 0, 0);
}

__device__ __forceinline__ void ld8(const float* __restrict__ p, float* v){
  float4 a = *(const float4*)p, b = *(const float4*)(p+4);
  v[0]=a.x; v[1]=a.y; v[2]=a.z; v[3]=a.w; v[4]=b.x; v[5]=b.y; v[6]=b.z; v[7]=b.w;
}

// ---- cheap agent-scope sync primitives (one L2 flush/inv per block, not per wave) ----
__device__ __forceinline__ int aadd_rlx(int* p, int v){
  return __hip_atomic_fetch_add(p, v, __ATOMIC_RELAXED, __HIP_MEMORY_SCOPE_AGENT);
}
__device__ __forceinline__ int ald_rlx(int* p){
  return __hip_atomic_load(p, __ATOMIC_RELAXED, __HIP_MEMORY_SCOPE_AGENT);
}
__device__ __forceinline__ void rel_fence(){ __builtin_amdgcn_fence(__ATOMIC_RELEASE, "agent"); }
__device__ __forceinline__ void acq_fence(){ __builtin_amdgcn_fence(__ATOMIC_ACQUIRE, "agent"); }

// grid barrier: __syncthreads drains vmcnt; thread0: optional release (wbl2),
// relaxed arrive, relaxed poll (no inv per poll!), one acquire (inv) on exit.
__device__ __forceinline__ void gridbar(int* bcnt, int& barid, bool rel){
  barid++;
  __syncthreads();
  if (threadIdx.x == 0){
    if (rel) rel_fence();
    aadd_rlx(bcnt, 1);
    const int target = NBLK * barid;
    while (ald_rlx(bcnt) < target) __builtin_amdgcn_s_sleep(8);
    acq_fence();
  }
  __syncthreads();
}

__global__ __launch_bounds__(256) void k_zero(float4* __restrict__ p, int n4){
  int i = blockIdx.x*256 + threadIdx.x;
  if (i < n4) p[i] = make_float4(0.f,0.f,0.f,0.f);
}

__global__ __launch_bounds__(256) void k_cvt_h(const float4* __restrict__ src,
    ushort4* __restrict__ dst, int n4){
  for (int i = blockIdx.x*256+threadIdx.x; i < n4; i += gridDim.x*256){
    float4 v = src[i];
    ushort4 o; o.x=f2bf(v.x); o.y=f2bf(v.y); o.z=f2bf(v.z); o.w=f2bf(v.w);
    dst[i]=o;
  }
}

// generic B-fragment swizzle: dst[nt][kt][lane][8]; (n,k) from up to 3 col-spaces
__global__ __launch_bounds__(256) void k_swz(u16* __restrict__ dst, int NT, int KT,
    const float* s0, int n0, int ld0, const float* s1, int n1, int ld1,
    const float* s2, int n2, int ld2)
{
  int gid = blockIdx.x*256+threadIdx.x;
  int total = NT*KT*64;
  if (gid >= total) return;
  int l = gid & 63;
  int kt = (gid >> 6) % KT;
  int nt = gid / (KT*64);
  int n = nt*16 + (l & 15);
  int k = kt*32 + ((l>>4)<<3);
  const float* sp = 0; int ld=0, col=0;
  if (n < n0){ sp=s0; ld=ld0; col=n; }
  else if (n < n0+n1){ sp=s1; ld=ld1; col=n-n0; }
  else if (n < n0+n1+n2){ sp=s2; ld=ld2; col=n-n0-n1; }
  short8 v;
  #pragma unroll 8
  for (int e=0;e<8;e++){
    float f = sp ? sp[(size_t)(k+e)*ld + col] : 0.f;
    v[e] = (short)f2bf(f);
  }
  *(short8*)(dst + (size_t)gid*8) = v;
}

// WstepF: K=1536 (g rows 0..1023, s rows 1024..1535), N=2560 (z cols, rec cols)
__global__ __launch_bounds__(256) void k_swz2(u16* __restrict__ dst,
    const float* __restrict__ W_gy, const float* __restrict__ W_sy,
    const float* __restrict__ W_gr, const float* __restrict__ W_sr)
{
  int gid = blockIdx.x*256+threadIdx.x;
  if (gid >= NBGEMM*48*64) return;
  int l = gid & 63;
  int kt = (gid >> 6) % 48;
  int nt = gid / (48*64);
  int n = nt*16 + (l & 15);
  int k = kt*32 + ((l>>4)<<3);
  short8 v;
  #pragma unroll 8
  for (int e=0;e<8;e++){
    int kk = k + e;
    float f;
    if (n < HH) f = (kk < H2) ? W_gy[(size_t)kk*HH + n]       : W_sy[(size_t)(kk-H2)*HH + n];
    else { int q = n-HH; f = (kk < H2) ? W_gr[(size_t)kk*H4 + q] : W_sr[(size_t)(kk-H2)*H4 + q]; }
    v[e] = (short)f2bf(f);
  }
  *(short8*)(dst + (size_t)gid*8) = v;
}

// one-time: hp = h @ W_h_att + b_att (MFMA) -> bf16
__global__ __launch_bounds__(256) void k_hproj(const float* __restrict__ h,
  const u16* __restrict__ WhF, const float* __restrict__ b_att, u16* __restrict__ hp)
{
  const int tid = threadIdx.x, l = tid & 63, wv = tid >> 6;
  const int wm = wv >> 1, wn = wv & 1;
  const int Mbase = blockIdx.x*128 + wm*64;
  const int Nbase = blockIdx.y*128 + wn*64;
  const int arow = l & 15, ak = (l>>4)<<3;
  f32x4 acc[4][4] = {};
  for (int kt=0; kt<32; kt++){
    short8 a[4], b[4];
    #pragma unroll
    for (int mt=0;mt<4;mt++){
      const float* p = h + (size_t)(Mbase + mt*16 + arow)*H2 + kt*32 + ak;
      float vv[8]; ld8(p, vv);
      short8 t;
      #pragma unroll 8
      for (int e=0;e<8;e++) t[e] = (short)f2bf(vv[e]);
      a[mt]=t;
    }
    #pragma unroll
    for (int nt=0;nt<4;nt++){
      int ntg = (Nbase>>4) + nt;
      b[nt] = *(const short8*)(WhF + (((size_t)ntg*32 + kt)*64 + l)*8);
    }
    #pragma unroll
    for (int mt=0;mt<4;mt++)
      #pragma unroll
      for (int nt=0;nt<4;nt++)
        acc[mt][nt] = mfma16(a[mt], b[nt], acc[mt][nt]);
  }
  #pragma unroll
  for (int mt=0;mt<4;mt++)
    #pragma unroll
    for (int nt=0;nt<4;nt++){
      int n = Nbase + nt*16 + (l&15);
      float bias = b_att[n];
      #pragma unroll
      for (int r=0;r<4;r++){
        int row = Mbase + mt*16 + ((l>>4)<<2) + r;
        hp[(size_t)row*HH + n] = f2bf(acc[mt][nt][r] + bias);
      }
    }
}

// final: out = zF @ WyyF + b_yy   M=3200 N=10240(pad) K=512
__global__ __launch_bounds__(256) void k_ybig(const u16* __restrict__ zF,
  const u16* __restrict__ WyyF, const float* __restrict__ b_yy, float* __restrict__ out)
{
  const int tid=threadIdx.x, l=tid&63, wv=tid>>6;
  const int wm=wv>>1, wn=wv&1;
  const int mtB = blockIdx.x*8 + wm*4;
  const int ntB = blockIdx.y*8 + wn*4;
  f32x4 acc[4][4] = {};
  for (int kt=0; kt<16; kt++){
    short8 a[4], b[4];
    #pragma unroll
    for (int mt=0;mt<4;mt++)
      a[mt] = *(const short8*)(zF + (((size_t)(mtB+mt)*16 + kt)*64 + l)*8);
    #pragma unroll
    for (int nt=0;nt<4;nt++)
      b[nt] = *(const short8*)(WyyF + (((size_t)(ntB+nt)*16 + kt)*64 + l)*8);
    #pragma unroll
    for (int mt=0;mt<4;mt++)
      #pragma unroll
      for (int nt=0;nt<4;nt++)
        acc[mt][nt] = mfma16(a[mt], b[nt], acc[mt][nt]);
  }
  #pragma unroll
  for (int mt=0;mt<4;mt++)
    #pragma unroll
    for (int nt=0;nt<4;nt++){
      int n = (ntB+nt)*16 + (l&15);
      if (n < VV){
        float bias = b_yy[n];
        #pragma unroll
        for (int r=0;r<4;r++){
          int row = (mtB+mt)*16 + ((l>>4)<<2) + r;
          out[(size_t)row*VV + n] = acc[mt][nt][r] + bias;
        }
      }
    }
}

// ======== the whole 100-step scan: one cooperative kernel ========
__global__ __launch_bounds__(512) void k_scan(
  const u16* __restrict__ hp, const u16* __restrict__ hb,
  const float* __restrict__ w_att, const int* __restrict__ seq,
  float* __restrict__ proj_att, float* __restrict__ gpart, float* __restrict__ Zpart,
  u16* __restrict__ aF, const u16* __restrict__ WstepF, const u16* __restrict__ WprojF,
  const float* __restrict__ b_gy, const float* __restrict__ b_sy,
  const float* __restrict__ b_sr, const float* __restrict__ b_gr,
  const float* __restrict__ E_yr, const int* __restrict__ labels,
  u16* __restrict__ zF, float* __restrict__ rec, float* __restrict__ cbuf,
  int* cnts)
{
  const int bid = blockIdx.x, tid = threadIdx.x;
  const int lane = tid & 63, wv = tid >> 6;
  __shared__ union {
    float sg[8][1024];
    float sC[8][64][8];
    float sS[32][516];
  } sm;
  __shared__ float szz[8];
  __shared__ int sflag;
  int barid = 0;
  const int fb = bid >> 3, fch = bid & 7;
  int* cnt_fb = cnts + fb*32;     // one 128B line per batch counter
  int* cntB   = cnts + 1024;
  int* bcnt   = cnts + 1056;
  const int flen = seq[fb];
  const int ft0 = fch * 125;
  float wa[8];
  ld8(w_att + lane*8, wa);

  for (int ls = 0; ls < LL; ++ls){
    // ===== phase A: flash attention partials + last-block combine =====
    {
      float sw[8];
      ld8(proj_att + fb*HH + lane*8, sw);
      const int tmax = min(ft0 + 125, flen);
      float gacc[16];
      #pragma unroll 16
      for (int i=0;i<16;i++) gacc[i]=0.f;
      float zacc = 0.f;
      for (int t = ft0 + wv; t < tmax; t += 8){
        const uint4 hv = *(const uint4*)(hp + ((size_t)fb*TT + t)*HH + lane*8);
        u32 uu[4] = {hv.x,hv.y,hv.z,hv.w};
        float p = 0.f;
        #pragma unroll
        for (int q=0;q<4;q++){
          p += wa[2*q+0]*fast_tanh(bf2f((u16)(uu[q]&0xffffu))+sw[2*q+0]);
          p += wa[2*q+1]*fast_tanh(bf2f((u16)(uu[q]>>16))+sw[2*q+1]);
        }
        #pragma unroll
        for (int off=32; off; off>>=1) p += __shfl_xor(p, off, 64);
        float wgt = __expf(p);
        zacc += wgt;
        const uint4* hr = (const uint4*)(hb + ((size_t)fb*TT + t)*H2 + lane*16);
        uint4 h0 = hr[0], h1 = hr[1];
        u32 hh[8] = {h0.x,h0.y,h0.z,h0.w,h1.x,h1.y,h1.z,h1.w};
        #pragma unroll
        for (int q=0;q<8;q++){
          gacc[2*q+0] += wgt*bf2f((u16)(hh[q]&0xffffu));
          gacc[2*q+1] += wgt*bf2f((u16)(hh[q]>>16));
        }
      }
      #pragma unroll
      for (int q=0;q<4;q++)
        *(float4*)(&sm.sg[wv][lane*16+q*4]) = make_float4(gacc[4*q],gacc[4*q+1],gacc[4*q+2],gacc[4*q+3]);
      if (lane==0) szz[wv]=zacc;
      __syncthreads();
      {
        int e = tid*2;
        float v0=0.f, v1=0.f;
        #pragma unroll
        for (int w8=0;w8<8;w8++){ v0 += sm.sg[w8][e]; v1 += sm.sg[w8][e+1]; }
        *(float2*)(gpart + ((size_t)(fb*8+fch))*H2 + e) = make_float2(v0,v1);
        if (tid==0){
          float z=0.f;
          #pragma unroll
          for (int w8=0;w8<8;w8++) z += szz[w8];
          Zpart[fb*8+fch] = z;
        }
      }
      __syncthreads();                 // drains vmcnt (compiler) - gpart in L2
      if (tid==0){
        rel_fence();                   // one wbl2 per block
        int old = aadd_rlx(cnt_fb, 1);
        sflag = (old == 8*ls + 7);
        if (sflag) acq_fence();        // combiner sees the other 7 blocks' partials
      }
      __syncthreads();
      if (sflag){                      // last block for batch fb: combine -> aF (g part)
        float z = 0.f;
        #pragma unroll
        for (int c=0;c<8;c++) z += Zpart[fb*8+c];
        float inv = 1.f/z;
        const int mt = fb>>4, bl = fb&15;
        for (int q = tid; q < H2; q += 512){
          float s = 0.f;
          #pragma unroll
          for (int c=0;c<8;c++) s += gpart[((size_t)(fb*8+c))*H2 + q];
          int kt = q>>5, j=(q>>3)&3, e=q&7;
          aF[((size_t)(kt*2+mt)*64 + 16*j + bl)*8 + e] = f2bf(s*inv);
        }
      }
      gridbar(bcnt, barid, sflag != 0);  // only combiners re-flush
    }
    // ===== phase B: [g|s](32x1536) @ Wstep(1536x2560) -> z->zF, rec =====
    {
      if (bid < NBGEMM){
        const int nt = bid;
        f32x4 acc0 = {0.f,0.f,0.f,0.f}, acc1 = {0.f,0.f,0.f,0.f};
        #pragma unroll
        for (int kk=0; kk<6; ++kk){
          int kt = wv*6 + kk;
          short8 bfr = *(const short8*)(WstepF + (((size_t)nt*48 + kt)*64 + lane)*8);
          short8 a0  = *(const short8*)(aF + ((size_t)(kt*2+0)*64 + lane)*8);
          short8 a1  = *(const short8*)(aF + ((size_t)(kt*2+1)*64 + lane)*8);
          acc0 = mfma16(a0, bfr, acc0);
          acc1 = mfma16(a1, bfr, acc1);
        }
        #pragma unroll
        for (int r=0;r<4;r++){ sm.sC[wv][lane][r] = acc0[r]; sm.sC[wv][lane][4+r] = acc1[r]; }
        __syncthreads();
        int lq = tid>>3, e = tid&7;
        float v = 0.f;
        #pragma unroll
        for (int w8=0;w8<8;w8++) v += sm.sC[w8][lq][e];
        int mtv = e>>2, r = e&3;
        int brow = mtv*16 + ((lq>>4)<<2) + r;
        int n = nt*16 + (lq&15);
        if (n < HH){
          float zv = fast_tanh(v + b_gy[n] + b_sy[n]);
          int row = brow*LL + ls;
          int mtg = row>>4, rr = row&15, ktz = n>>5;
          int lp = rr | (((n>>3)&3)<<4);
          zF[(((size_t)mtg*16+ktz)*64+lp)*8 + (n&7)] = f2bf(zv);
        } else {
          int q = n - HH;
          int tok = labels[brow*LL + ls];
          rec[(size_t)brow*H4 + q] = v + b_sr[q] + b_gr[q] + E_yr[(size_t)tok*H4 + q];
        }
      }
      __syncthreads();                 // rec/zF drained to L2
      if (tid==0){
        if (bid < NBGEMM){
          rel_fence();
          int old = aadd_rlx(cntB, 1);
          sflag = (old == NBGEMM*(ls+1) - 1);
          if (sflag) acq_fence();      // finisher sees all rec columns
        } else sflag = 0;
      }
      __syncthreads();
      // ===== phase C (finisher block): LSTM + s-frags + proj_att GEMM =====
      if (sflag){
        const int b = tid>>4, q0 = (tid&15)*32;
        const float* rb  = rec + (size_t)b*H4;
        const float* cin = cbuf + (size_t)(ls&1)*BB*HH + b*HH;
        float*      cout = cbuf + (size_t)((ls+1)&1)*BB*HH + b*HH;
        const int mt = b>>4, bl = b&15;
        for (int qq=q0; qq<q0+32; qq+=8){
          float iv[8],fv[8],gv[8],ov[8],cv[8];
          ld8(rb+qq,iv); ld8(rb+HH+qq,fv); ld8(rb+H2+qq,gv); ld8(rb+1536+qq,ov);
          ld8(cin+qq,cv);
          float sv[8], cn[8];
          #pragma unroll 8
          for (int e=0;e<8;e++){
            float ii = sigm(iv[e]), ff = sigm(fv[e]);
            float cg = fast_tanh(gv[e]), oo = sigm(ov[e]);
            cn[e] = ff*cv[e] + ii*cg;
            sv[e] = oo*fast_tanh(cn[e]);
          }
          *(float4*)(cout+qq)   = make_float4(cn[0],cn[1],cn[2],cn[3]);
          *(float4*)(cout+qq+4) = make_float4(cn[4],cn[5],cn[6],cn[7]);
          #pragma unroll 8
          for (int e=0;e<8;e++){
            int q = qq+e;
            sm.sS[b][q] = sv[e];
            int kt = 32 + (q>>5), j=(q>>3)&3;
            aF[((size_t)(kt*2+mt)*64 + 16*j + bl)*8 + (q&7)] = f2bf(sv[e]);
          }
        }
        __syncthreads();
        f32x4 p0[4] = {}, p1[4] = {};
        for (int kt=0; kt<16; ++kt){
          int kbase = kt*32 + ((lane>>4)<<3);
          short8 a0, a1;
          {
            float vv[8];
            ld8(&sm.sS[lane&15][kbase], vv);
            #pragma unroll 8
            for (int e=0;e<8;e++) a0[e] = (short)f2bf(vv[e]);
            ld8(&sm.sS[16+(lane&15)][kbase], vv);
            #pragma unroll 8
            for (int e=0;e<8;e++) a1[e] = (short)f2bf(vv[e]);
          }
          #pragma unroll
          for (int j=0;j<4;j++){
            int nt2 = wv*4 + j;
            short8 bfr = *(const short8*)(WprojF + (((size_t)nt2*16 + kt)*64 + lane)*8);
            p0[j] = mfma16(a0, bfr, p0[j]);
            p1[j] = mfma16(a1, bfr, p1[j]);
          }
        }
        #pragma unroll
        for (int j=0;j<4;j++){
          int n = (wv*4+j)*16 + (lane&15);
          #pragma unroll
          for (int r=0;r<4;r++){
            int b0 = ((lane>>4)<<2) + r;
            proj_att[(size_t)b0*HH + n]      = p0[j][r];
            proj_att[(size_t)(16+b0)*HH + n] = p1[j][r];
          }
        }
      }
      gridbar(bcnt, barid, sflag != 0);   // only the finisher re-flushes
    }
  }
}

extern "C" void kernel_launch(void* const* d_in, const int* in_sizes, int n_in,
                              void* d_out, int out_size, void* d_ws, size_t ws_size,
                              hipStream_t stream)
{
  (void)in_sizes; (void)n_in; (void)out_size; (void)ws_size;
  const float* h       = (const float*)d_in[0];
  const int*   seq     = (const int*)d_in[1];
  const int*   labels  = (const int*)d_in[2];
  const float* W_sy    = (const float*)d_in[3];
  const float* b_sy    = (const float*)d_in[4];
  const float* W_gy    = (const float*)d_in[5];
  const float* b_gy    = (const float*)d_in[6];
  const float* W_yy    = (const float*)d_in[7];
  const float* b_yy    = (const float*)d_in[8];
  const float* E_yr    = (const float*)d_in[9];
  const float* W_sr    = (const float*)d_in[10];
  const float* b_sr    = (const float*)d_in[11];
  const float* W_gr    = (const float*)d_in[12];
  const float* b_gr    = (const float*)d_in[13];
  const float* W_s_att = (const float*)d_in[14];
  const float* W_h_att = (const float*)d_in[15];
  const float* b_att   = (const float*)d_in[16];
  const float* w_att   = (const float*)d_in[17];
  float* out = (float*)d_out;

  char* w = (char*)d_ws;
  u16* hp      = (u16*)w;  w += (size_t)BB*TT*HH*2;          // 32.77 MB
  u16* hb      = (u16*)w;  w += (size_t)BB*TT*H2*2;          // 65.54 MB
  u16* WhF     = (u16*)w;  w += (size_t)32*32*64*8*2;        // 1.05 MB
  u16* WstepF  = (u16*)w;  w += (size_t)NBGEMM*48*64*8*2;    // 7.86 MB
  u16* WprojF  = (u16*)w;  w += (size_t)32*16*64*8*2;        // 0.52 MB
  u16* WyyF    = (u16*)w;  w += (size_t)640*16*64*8*2;       // 10.49 MB
  u16* zF      = (u16*)w;  w += (size_t)200*16*64*8*2;       // 3.28 MB
  float* gpart = (float*)w; w += (size_t)BB*8*H2*4;          // 1.05 MB
  float* Zpart = (float*)w; w += (size_t)BB*8*4;
  float* rec   = (float*)w; w += (size_t)BB*H4*4;
  // ---- zeroed-every-call region (contiguous) ----
  float* zbase    = (float*)w;
  float* proj_att = (float*)w; w += (size_t)BB*HH*4;         // 16384 f
  float* cbuf     = (float*)w; w += (size_t)2*BB*HH*4;       // 32768 f
  u16*   aF       = (u16*)w;  w += (size_t)48*2*64*8*2;      // 49152 u16 = 24576 f
  int*   cnts     = (int*)w;  w += 8192;                     // 2048 ints, line-padded
  const int nzero4 = (16384 + 32768 + 24576 + 2048) / 4;     // 18944 float4

  k_cvt_h<<<2048,256,0,stream>>>((const float4*)h, (ushort4*)hb, BB*TT*H2/4);
  k_swz<<<256 ,256,0,stream>>>(WhF,   32,32, W_h_att,512,512, 0,0,0, 0,0,0);
  k_swz2<<<1920,256,0,stream>>>(WstepF, W_gy, W_sy, W_gr, W_sr);
  k_swz<<<128 ,256,0,stream>>>(WprojF, 32,16, W_s_att,512,512, 0,0,0, 0,0,0);
  k_swz<<<2560,256,0,stream>>>(WyyF, 640,16, W_yy,10000,10000, 0,0,0, 0,0,0);
  k_zero<<<(nzero4+255)/256,256,0,stream>>>((float4*)zbase, nzero4);
  k_hproj<<<dim3(250,4),256,0,stream>>>(h, WhF, b_att, hp);

  void* args[] = { (void*)&hp, (void*)&hb, (void*)&w_att, (void*)&seq,
                   (void*)&proj_att, (void*)&gpart, (void*)&Zpart, (void*)&aF,
                   (void*)&WstepF, (void*)&WprojF,
                   (void*)&b_gy, (void*)&b_sy, (void*)&b_sr, (void*)&b_gr,
                   (void*)&E_yr, (void*)&labels, (void*)&zF, (void*)&rec,
                   (void*)&cbuf, (void*)&cnts };
  hipLaunchCooperativeKernel((const void*)k_scan, dim3(NBLK), dim3(512), args, 0, stream);

  k_ybig<<<dim3(25,80),256,0,stream>>>(zF, WyyF, b_yy, out);
}